// Round 8
// baseline (1523.969 us; speedup 1.0000x reference)
//
#include <hip/hip_runtime.h>

// Chamfer distance via bf16 MFMA with hi/lo split (fp32-grade precision).
// d(p,q) = ||p||^2 + ||q||^2 - 2 p.q.
// A row (target): [uh x3, uh x3, ul x3, ul x3, wh wm wl, 0], u=-2t, w=||t||^2
// B col (query):  [qh x3, ql x3, qh x3, ql x3, 1 1 1, 0]
// => D = -2 t.q + ||t||^2 + O(1e-5); query ||q||^2 added after the min.
// nn: 512 threads / 8 waves, 512 queries per block (2 B-sets per wave,
// 2 MFMA per ds_read), grid 256 = 1 block/CU. Double-buffered LDS with
// register-staged prefetch, ONE barrier per stage, 32-tile loop fully
// unrolled with immediate offsets. 3 graph nodes total.

typedef short bf16x8 __attribute__((ext_vector_type(8)));
typedef float f32x16 __attribute__((ext_vector_type(16)));

#define B_SZ   8
#define NPTS   8192
#define TOTAL  (B_SZ * NPTS)     // 65536
#define BLOCK  256               // prep block
#define NNB    512               // nn block: 8 waves
#define QB     512               // queries per nn block
#define SLICE  1024              // targets per LDS stage
#define NSTAGE (NPTS / SLICE)    // 8
#define TILES  (SLICE / 32)      // 32

// round-to-nearest bf16 (half-up via +0x8000 carry), return remainder
__device__ __forceinline__ unsigned short bf16rn(float f, float* rem) {
    unsigned u = __float_as_uint(f);
    unsigned h = (u + 0x8000u) & 0xFFFF0000u;
    *rem = f - __uint_as_float(h);
    return (unsigned short)(h >> 16);
}

// One thread per point; blockIdx.y: 0 = gt, 1 = pred.  (round-4/6/7 exact)
__global__ __launch_bounds__(BLOCK) void chamfer_prep_mfma(
    const float* __restrict__ gt, const float* __restrict__ pred,
    uint4* __restrict__ TgA, uint4* __restrict__ TgB, float* __restrict__ Wg,
    uint4* __restrict__ TpA, uint4* __restrict__ TpB, float* __restrict__ Wp)
{
    int i = blockIdx.x * BLOCK + threadIdx.x;
    const float* src = blockIdx.y ? pred : gt;
    uint4* TA = blockIdx.y ? TpA : TgA;
    uint4* TB = blockIdx.y ? TpB : TgB;
    float* W  = blockIdx.y ? Wp  : Wg;

    float x = src[3 * (size_t)i + 0];
    float y = src[3 * (size_t)i + 1];
    float z = src[3 * (size_t)i + 2];
    float w = fmaf(x, x, fmaf(y, y, z * z));
    W[i] = w;

    float ux = -2.f * x, uy = -2.f * y, uz = -2.f * z;
    float rx, ry, rz, dx, dy, dz, rw1, rw2, rw3;
    unsigned short uhx = bf16rn(ux, &rx), uhy = bf16rn(uy, &ry), uhz = bf16rn(uz, &rz);
    unsigned short ulx = bf16rn(rx, &dx), uly = bf16rn(ry, &dy), ulz = bf16rn(rz, &dz);
    unsigned short wh = bf16rn(w, &rw1), wm = bf16rn(rw1, &rw2), wl = bf16rn(rw2, &rw3);
    union { unsigned short s[16]; uint4 v[2]; } A;
    A.s[0] = uhx; A.s[1] = uhy; A.s[2]  = uhz;
    A.s[3] = uhx; A.s[4] = uhy; A.s[5]  = uhz;
    A.s[6] = ulx; A.s[7] = uly; A.s[8]  = ulz;
    A.s[9] = ulx; A.s[10] = uly; A.s[11] = ulz;
    A.s[12] = wh; A.s[13] = wm; A.s[14] = wl; A.s[15] = 0;
    TA[2 * (size_t)i]     = A.v[0];
    TA[2 * (size_t)i + 1] = A.v[1];

    float sx, sy, sz, ex, ey, ez;
    unsigned short qhx = bf16rn(x, &sx), qhy = bf16rn(y, &sy), qhz = bf16rn(z, &sz);
    unsigned short qlx = bf16rn(sx, &ex), qly = bf16rn(sy, &ey), qlz = bf16rn(sz, &ez);
    union { unsigned short s[16]; uint4 v[2]; } Bb;
    Bb.s[0] = qhx; Bb.s[1] = qhy; Bb.s[2]  = qhz;
    Bb.s[3] = qlx; Bb.s[4] = qly; Bb.s[5]  = qlz;
    Bb.s[6] = qhx; Bb.s[7] = qhy; Bb.s[8]  = qhz;
    Bb.s[9] = qlx; Bb.s[10] = qly; Bb.s[11] = qlz;
    Bb.s[12] = 0x3F80; Bb.s[13] = 0x3F80; Bb.s[14] = 0x3F80; Bb.s[15] = 0;
    TB[2 * (size_t)i]     = Bb.v[0];
    TB[2 * (size_t)i + 1] = Bb.v[1];
}

// m = min(m, d[0..15]) : min3-fusable triples (8 x v_min3_f32 when fused)
__device__ __forceinline__ float minred(f32x16 d, float m) {
    float r0 = fminf(fminf(d[0], d[1]), d[2]);
    float r1 = fminf(fminf(d[3], d[4]), d[5]);
    float r2 = fminf(fminf(d[6], d[7]), d[8]);
    float r3 = fminf(fminf(d[9], d[10]), d[11]);
    float r4 = fminf(fminf(d[12], d[13]), d[14]);
    float s0 = fminf(fminf(r0, r1), r2);
    float s1 = fminf(fminf(r3, r4), d[15]);
    return fminf(fminf(m, s0), s1);
}

// grid (NPTS/QB=16, B_SZ=8, 2 dirs), 512 threads / 8 waves, 1 block/CU.
// Wave w covers queries qb*512 + w*64 .. +63 (two 32-col B-sets).
__global__ __launch_bounds__(NNB, 2) void chamfer_nn_fused(
    const uint4* __restrict__ TgA, const uint4* __restrict__ TpB,
    const float* __restrict__ Wp,
    const uint4* __restrict__ TpA, const uint4* __restrict__ TgB,
    const float* __restrict__ Wg,
    float* __restrict__ out)
{
    __shared__ uint4 tileU[2 * SLICE * 2];   // 2 x 32 KiB A-form buffers
    __shared__ float psum[8];
    char* tileC = (char*)tileU;

    const int qb = blockIdx.x, b = blockIdx.y, dir = blockIdx.z;
    const int t = threadIdx.x, lane = t & 63, wid = t >> 6;
    const int col = lane & 31, hi = lane >> 5;

    const uint4* TA = dir ? TpA : TgA;
    const uint4* TB = dir ? TgB : TpB;
    const float* WQ = dir ? Wg  : Wp;

    // B fragments (round-4/6 exact addressing): wave covers queries
    // qblk..qblk+63 as two 32-column sets
    const int qblk = qb * QB + wid * 64;
    const char* TBc = (const char*)(TB + ((size_t)b * NPTS + qblk) * 2);
    bf16x8 bq0 = *(const bf16x8*)(TBc + (size_t)col * 32 + hi * 16);
    bf16x8 bq1 = *(const bf16x8*)(TBc + (size_t)(col + 32) * 32 + hi * 16);

    f32x16 zacc;
#pragma unroll
    for (int j = 0; j < 16; ++j) zacc[j] = 0.f;
    float m0 = 3.0e38f, m1 = 3.0e38f;
    // swizzled A-frag base; per-tile offset is the imm tt*1024
    const int abase = (col * 32 + hi * 16) ^ (((col >> 2) & 7) << 4);

    const uint4* TAb = TA + (size_t)b * NPTS * 2;

    // prologue: stage 0 into buf0 (granule-swizzled copy, round-6 exact form)
    {
#pragma unroll
        for (int it = 0; it < (SLICE * 2) / NNB; ++it) {
            int g = t + it * NNB;
            uint4 v = TAb[g];
            int tl = g >> 1, gh = g & 1;
            int off = (tl * 32 + gh * 16) ^ (((tl >> 2) & 7) << 4);
            *(uint4*)(tileC + off) = v;
        }
        __syncthreads();
    }

    for (int st = 0; st < NSTAGE; ++st) {
        const int cur = (st & 1) << 15;      // current buffer byte offset
        uint4 rg[4];
        if (st + 1 < NSTAGE) {               // issue next-stage loads EARLY
            const uint4* srcA = TAb + (size_t)(st + 1) * SLICE * 2;
#pragma unroll
            for (int it = 0; it < 4; ++it) rg[it] = srcA[t + it * NNB];
        }

#pragma unroll
        for (int tt = 0; tt < TILES; ++tt) {
            bf16x8 a = *(const bf16x8*)(tileC + cur + abase + tt * 1024);
            f32x16 d0 = __builtin_amdgcn_mfma_f32_32x32x16_bf16(a, bq0, zacc, 0, 0, 0);
            f32x16 d1 = __builtin_amdgcn_mfma_f32_32x32x16_bf16(a, bq1, zacc, 0, 0, 0);
            m0 = minred(d0, m0);
            m1 = minred(d1, m1);
        }

        if (st + 1 < NSTAGE) {               // write-late into the OTHER buffer
            const int nxt = cur ^ 32768;
#pragma unroll
            for (int it = 0; it < 4; ++it) {
                int g = t + it * NNB;
                int tl = g >> 1, gh = g & 1;
                int off = (tl * 32 + gh * 16) ^ (((tl >> 2) & 7) << 4);
                *(uint4*)(tileC + nxt + off) = rg[it];
            }
        }
        __syncthreads();                     // one barrier per stage
    }

    // epilogue (round-6 exact mapping, 8 waves): combine row-halves, add ||q||^2
    m0 = fminf(m0, __shfl_xor(m0, 32));
    m1 = fminf(m1, __shfl_xor(m1, 32));
    // thread t <-> query qb*QB + t  (lane<32: m0 ; lane>=32: m1)
    float wq = WQ[(size_t)b * NPTS + qb * QB + t];
    float d = fmaxf((lane < 32 ? m0 : m1) + wq, 0.0f);
    float s = d;
#pragma unroll
    for (int o = 1; o < 64; o <<= 1) s += __shfl_xor(s, o);
    if (lane == 0) psum[wid] = s;
    __syncthreads();
    if (t == 0) {
        float tot = ((psum[0] + psum[1]) + (psum[2] + psum[3]))
                  + ((psum[4] + psum[5]) + (psum[6] + psum[7]));
        atomicAdd(out, tot * (1.0f / (float)TOTAL));
    }
}

extern "C" void kernel_launch(void* const* d_in, const int* in_sizes, int n_in,
                              void* d_out, int out_size, void* d_ws, size_t ws_size,
                              hipStream_t stream) {
    const float* pred = (const float*)d_in[0];   // [B, N, 3]
    const float* gt   = (const float*)d_in[1];   // [B, M, 3]
    float* out = (float*)d_out;

    // ws layout: TgA, TpA, TgB, TpB (32B/point), Wg, Wp
    char* ws = (char*)d_ws;
    uint4* TgA = (uint4*)(ws);
    uint4* TpA = (uint4*)(ws + (size_t)TOTAL * 32);
    uint4* TgB = (uint4*)(ws + (size_t)TOTAL * 64);
    uint4* TpB = (uint4*)(ws + (size_t)TOTAL * 96);
    float* Wg  = (float*)(ws + (size_t)TOTAL * 128);
    float* Wp  = (float*)(ws + (size_t)TOTAL * 128 + (size_t)TOTAL * 4);

    hipMemsetAsync(out, 0, sizeof(float), stream);

    chamfer_prep_mfma<<<dim3(TOTAL / BLOCK, 2), BLOCK, 0, stream>>>(
        gt, pred, TgA, TgB, Wg, TpA, TpB, Wp);

    chamfer_nn_fused<<<dim3(NPTS / QB, B_SZ, 2), NNB, 0, stream>>>(
        TgA, TpB, Wp, TpA, TgB, Wg, out);
}

// Round 9
// 108.008 us; speedup vs baseline: 14.1098x; 14.1098x over previous
//
#include <hip/hip_runtime.h>

// Chamfer distance via bf16 MFMA with hi/lo split (fp32-grade precision).
// d(p,q) = ||p||^2 + ||q||^2 - 2 p.q.
// A row (target): [uh x3, uh x3, ul x3, ul x3, wh wm wl, 0], u=-2t, w=||t||^2
// B col (query):  [qh x3, ql x3, qh x3, ql x3, 1 1 1, 0]
// => D = -2 t.q + ||t||^2 + O(1e-5); query ||q||^2 added after the min.
// nn: R6-proven geometry (256 thr / 4 waves, 2 B-sets per wave, unroll 2 —
// 44-VGPR no-spill loop body) + R8-proven double-buffered staging (loads
// issued before compute, ds_write-late to other buffer, ONE barrier/stage).
// NOTE: full unroll of the tile loop caused scratch spill (R8, 15x slower) —
// keep #pragma unroll 2.

typedef short bf16x8 __attribute__((ext_vector_type(8)));
typedef float f32x16 __attribute__((ext_vector_type(16)));

#define B_SZ   8
#define NPTS   8192
#define TOTAL  (B_SZ * NPTS)     // 65536
#define BLOCK  256               // prep + nn block
#define QB     256               // queries per nn block
#define SLICE  1024              // targets per LDS stage
#define NSTAGE (NPTS / SLICE)    // 8
#define TILES  (SLICE / 32)      // 32
#define GRANS  ((SLICE * 2) / BLOCK)   // 8 granules per thread per stage

// round-to-nearest bf16 (half-up via +0x8000 carry), return remainder
__device__ __forceinline__ unsigned short bf16rn(float f, float* rem) {
    unsigned u = __float_as_uint(f);
    unsigned h = (u + 0x8000u) & 0xFFFF0000u;
    *rem = f - __uint_as_float(h);
    return (unsigned short)(h >> 16);
}

// One thread per point; blockIdx.y: 0 = gt, 1 = pred.  (round-4/6 exact)
__global__ __launch_bounds__(BLOCK) void chamfer_prep_mfma(
    const float* __restrict__ gt, const float* __restrict__ pred,
    uint4* __restrict__ TgA, uint4* __restrict__ TgB, float* __restrict__ Wg,
    uint4* __restrict__ TpA, uint4* __restrict__ TpB, float* __restrict__ Wp)
{
    int i = blockIdx.x * BLOCK + threadIdx.x;
    const float* src = blockIdx.y ? pred : gt;
    uint4* TA = blockIdx.y ? TpA : TgA;
    uint4* TB = blockIdx.y ? TpB : TgB;
    float* W  = blockIdx.y ? Wp  : Wg;

    float x = src[3 * (size_t)i + 0];
    float y = src[3 * (size_t)i + 1];
    float z = src[3 * (size_t)i + 2];
    float w = fmaf(x, x, fmaf(y, y, z * z));
    W[i] = w;

    float ux = -2.f * x, uy = -2.f * y, uz = -2.f * z;
    float rx, ry, rz, dx, dy, dz, rw1, rw2, rw3;
    unsigned short uhx = bf16rn(ux, &rx), uhy = bf16rn(uy, &ry), uhz = bf16rn(uz, &rz);
    unsigned short ulx = bf16rn(rx, &dx), uly = bf16rn(ry, &dy), ulz = bf16rn(rz, &dz);
    unsigned short wh = bf16rn(w, &rw1), wm = bf16rn(rw1, &rw2), wl = bf16rn(rw2, &rw3);
    union { unsigned short s[16]; uint4 v[2]; } A;
    A.s[0] = uhx; A.s[1] = uhy; A.s[2]  = uhz;
    A.s[3] = uhx; A.s[4] = uhy; A.s[5]  = uhz;
    A.s[6] = ulx; A.s[7] = uly; A.s[8]  = ulz;
    A.s[9] = ulx; A.s[10] = uly; A.s[11] = ulz;
    A.s[12] = wh; A.s[13] = wm; A.s[14] = wl; A.s[15] = 0;
    TA[2 * (size_t)i]     = A.v[0];
    TA[2 * (size_t)i + 1] = A.v[1];

    float sx, sy, sz, ex, ey, ez;
    unsigned short qhx = bf16rn(x, &sx), qhy = bf16rn(y, &sy), qhz = bf16rn(z, &sz);
    unsigned short qlx = bf16rn(sx, &ex), qly = bf16rn(sy, &ey), qlz = bf16rn(sz, &ez);
    union { unsigned short s[16]; uint4 v[2]; } Bb;
    Bb.s[0] = qhx; Bb.s[1] = qhy; Bb.s[2]  = qhz;
    Bb.s[3] = qlx; Bb.s[4] = qly; Bb.s[5]  = qlz;
    Bb.s[6] = qhx; Bb.s[7] = qhy; Bb.s[8]  = qhz;
    Bb.s[9] = qlx; Bb.s[10] = qly; Bb.s[11] = qlz;
    Bb.s[12] = 0x3F80; Bb.s[13] = 0x3F80; Bb.s[14] = 0x3F80; Bb.s[15] = 0;
    TB[2 * (size_t)i]     = Bb.v[0];
    TB[2 * (size_t)i + 1] = Bb.v[1];
}

// m = min(m, d[0..15]) : min3-fusable triples (8 x v_min3_f32 when fused)
__device__ __forceinline__ float minred(f32x16 d, float m) {
    float r0 = fminf(fminf(d[0], d[1]), d[2]);
    float r1 = fminf(fminf(d[3], d[4]), d[5]);
    float r2 = fminf(fminf(d[6], d[7]), d[8]);
    float r3 = fminf(fminf(d[9], d[10]), d[11]);
    float r4 = fminf(fminf(d[12], d[13]), d[14]);
    float s0 = fminf(fminf(r0, r1), r2);
    float s1 = fminf(fminf(r3, r4), d[15]);
    return fminf(fminf(m, s0), s1);
}

// grid (NPTS/QB=32, B_SZ=8, 2 dirs), 256 threads / 4 waves.
// Wave w covers queries qb*256 + w*64 .. +63 (two 32-col B-sets).
// Double-buffered LDS: loads issued early, ds_write late, 1 barrier/stage.
__global__ __launch_bounds__(BLOCK, 2) void chamfer_nn_fused(
    const uint4* __restrict__ TgA, const uint4* __restrict__ TpB,
    const float* __restrict__ Wp,
    const uint4* __restrict__ TpA, const uint4* __restrict__ TgB,
    const float* __restrict__ Wg,
    float* __restrict__ out)
{
    __shared__ uint4 tileU[2 * SLICE * 2];   // 2 x 32 KiB A-form buffers
    __shared__ float psum[4];
    char* tileC = (char*)tileU;

    const int qb = blockIdx.x, b = blockIdx.y, dir = blockIdx.z;
    const int t = threadIdx.x, lane = t & 63, wid = t >> 6;
    const int col = lane & 31, hi = lane >> 5;

    const uint4* TA = dir ? TpA : TgA;
    const uint4* TB = dir ? TgB : TpB;
    const float* WQ = dir ? Wg  : Wp;

    // B fragments (round-4/6 exact addressing)
    const int qblk = qb * QB + wid * 64;
    const char* TBc = (const char*)(TB + ((size_t)b * NPTS + qblk) * 2);
    bf16x8 bq0 = *(const bf16x8*)(TBc + (size_t)col * 32 + hi * 16);
    bf16x8 bq1 = *(const bf16x8*)(TBc + (size_t)(col + 32) * 32 + hi * 16);

    f32x16 zacc;
#pragma unroll
    for (int j = 0; j < 16; ++j) zacc[j] = 0.f;
    float m0 = 3.0e38f, m1 = 3.0e38f;
    // swizzled A-frag base; per-tile offset is the imm tt*1024
    const int abase = (col * 32 + hi * 16) ^ (((col >> 2) & 7) << 4);

    const uint4* TAb = TA + (size_t)b * NPTS * 2;

    // prologue: stage 0 into buf0 (granule-swizzled copy, round-6 exact)
#pragma unroll
    for (int it = 0; it < GRANS; ++it) {
        int g = t + it * BLOCK;
        uint4 v = TAb[g];
        int tl = g >> 1, gh = g & 1;
        int off = (tl * 32 + gh * 16) ^ (((tl >> 2) & 7) << 4);
        *(uint4*)(tileC + off) = v;
    }
    __syncthreads();

    for (int st = 0; st < NSTAGE; ++st) {
        const int cur = (st & 1) << 15;      // current buffer byte offset
        uint4 rg[GRANS];
        if (st + 1 < NSTAGE) {               // issue next-stage loads EARLY
            const uint4* srcA = TAb + (size_t)(st + 1) * SLICE * 2;
#pragma unroll
            for (int it = 0; it < GRANS; ++it) rg[it] = srcA[t + it * BLOCK];
        }

        // R6-proven compute body (unroll 2 — full unroll spills, see R8)
#pragma unroll 2
        for (int tt = 0; tt < TILES; ++tt) {
            bf16x8 a = *(const bf16x8*)(tileC + cur + abase + tt * 1024);
            f32x16 d0 = __builtin_amdgcn_mfma_f32_32x32x16_bf16(a, bq0, zacc, 0, 0, 0);
            m0 = minred(d0, m0);
            f32x16 d1 = __builtin_amdgcn_mfma_f32_32x32x16_bf16(a, bq1, zacc, 0, 0, 0);
            m1 = minred(d1, m1);
        }

        if (st + 1 < NSTAGE) {               // write-late into the OTHER buffer
            const int nxt = cur ^ 32768;
#pragma unroll
            for (int it = 0; it < GRANS; ++it) {
                int g = t + it * BLOCK;
                int tl = g >> 1, gh = g & 1;
                int off = (tl * 32 + gh * 16) ^ (((tl >> 2) & 7) << 4);
                *(uint4*)(tileC + nxt + off) = rg[it];
            }
        }
        __syncthreads();                     // one barrier per stage
        // (stage st computed from buf[st&1]; writes went to buf[(st+1)&1],
        //  whose last readers were stage st-1 — already behind the previous
        //  barrier. Race-free with a single barrier. Proven in R8.)
    }

    // epilogue (round-6 exact mapping): combine row-halves, add ||q||^2
    m0 = fminf(m0, __shfl_xor(m0, 32));
    m1 = fminf(m1, __shfl_xor(m1, 32));
    // thread t <-> query qb*QB + t  (lane<32: m0 ; lane>=32: m1)
    float wq = WQ[(size_t)b * NPTS + qb * QB + t];
    float d = fmaxf((lane < 32 ? m0 : m1) + wq, 0.0f);
    float s = d;
#pragma unroll
    for (int o = 1; o < 64; o <<= 1) s += __shfl_xor(s, o);
    if (lane == 0) psum[wid] = s;
    __syncthreads();
    if (t == 0) {
        float tot = (psum[0] + psum[1]) + (psum[2] + psum[3]);
        atomicAdd(out, tot * (1.0f / (float)TOTAL));
    }
}

extern "C" void kernel_launch(void* const* d_in, const int* in_sizes, int n_in,
                              void* d_out, int out_size, void* d_ws, size_t ws_size,
                              hipStream_t stream) {
    const float* pred = (const float*)d_in[0];   // [B, N, 3]
    const float* gt   = (const float*)d_in[1];   // [B, M, 3]
    float* out = (float*)d_out;

    // ws layout: TgA, TpA, TgB, TpB (32B/point), Wg, Wp
    char* ws = (char*)d_ws;
    uint4* TgA = (uint4*)(ws);
    uint4* TpA = (uint4*)(ws + (size_t)TOTAL * 32);
    uint4* TgB = (uint4*)(ws + (size_t)TOTAL * 64);
    uint4* TpB = (uint4*)(ws + (size_t)TOTAL * 96);
    float* Wg  = (float*)(ws + (size_t)TOTAL * 128);
    float* Wp  = (float*)(ws + (size_t)TOTAL * 128 + (size_t)TOTAL * 4);

    hipMemsetAsync(out, 0, sizeof(float), stream);

    chamfer_prep_mfma<<<dim3(TOTAL / BLOCK, 2), BLOCK, 0, stream>>>(
        gt, pred, TgA, TgB, Wg, TpA, TpB, Wp);

    chamfer_nn_fused<<<dim3(NPTS / QB, B_SZ, 2), BLOCK, 0, stream>>>(
        TgA, TpB, Wp, TpA, TgB, Wg, out);
}

// Round 10
// 97.688 us; speedup vs baseline: 15.6004x; 1.1056x over previous
//
#include <hip/hip_runtime.h>

// Chamfer distance via bf16 MFMA with hi/lo split (fp32-grade precision).
// d(p,q) = ||p||^2 + ||q||^2 - 2 p.q.
// A row (target): [uh x3, uh x3, ul x3, ul x3, wh wm wl, 0], u=-2t, w=||t||^2
// B col (query):  [qh x3, ql x3, qh x3, ql x3, 1 1 1, 0]
// => D = -2 t.q + ||t||^2 + O(1e-5); query ||q||^2 added after the min.
// nn: R6 geometry (256 thr / 4 waves, QB=256, 2 MFMA per ds_read) +
//  - global_load_lds(16B) async staging, double-buffered, 1 barrier/stage
//    (no VGPR round-trip -> no spill; source pre-swizzled, LDS linear)
//  - elementwise f32x16 min accumulators (no loop-carried scalar chain)
//  - explicit a_nxt lookahead (hides ds_read_b128 latency)
// Spill history: R8 full-unroll spilled (3.4GB scratch), R9 rg[] staging
// spilled (80MB). Keep unroll 2 and zero-VGPR staging.

typedef short bf16x8 __attribute__((ext_vector_type(8)));
typedef float f32x16 __attribute__((ext_vector_type(16)));

#define B_SZ   8
#define NPTS   8192
#define TOTAL  (B_SZ * NPTS)     // 65536
#define BLOCK  256               // prep + nn block
#define QB     256               // queries per nn block
#define SLICE  1024              // targets per LDS stage
#define NSTAGE (NPTS / SLICE)    // 8
#define TILES  (SLICE / 32)      // 32

// round-to-nearest bf16 (half-up via +0x8000 carry), return remainder
__device__ __forceinline__ unsigned short bf16rn(float f, float* rem) {
    unsigned u = __float_as_uint(f);
    unsigned h = (u + 0x8000u) & 0xFFFF0000u;
    *rem = f - __uint_as_float(h);
    return (unsigned short)(h >> 16);
}

// One thread per point; blockIdx.y: 0 = gt, 1 = pred.  (round-4/6 exact)
__global__ __launch_bounds__(BLOCK) void chamfer_prep_mfma(
    const float* __restrict__ gt, const float* __restrict__ pred,
    uint4* __restrict__ TgA, uint4* __restrict__ TgB, float* __restrict__ Wg,
    uint4* __restrict__ TpA, uint4* __restrict__ TpB, float* __restrict__ Wp)
{
    int i = blockIdx.x * BLOCK + threadIdx.x;
    const float* src = blockIdx.y ? pred : gt;
    uint4* TA = blockIdx.y ? TpA : TgA;
    uint4* TB = blockIdx.y ? TpB : TgB;
    float* W  = blockIdx.y ? Wp  : Wg;

    float x = src[3 * (size_t)i + 0];
    float y = src[3 * (size_t)i + 1];
    float z = src[3 * (size_t)i + 2];
    float w = fmaf(x, x, fmaf(y, y, z * z));
    W[i] = w;

    float ux = -2.f * x, uy = -2.f * y, uz = -2.f * z;
    float rx, ry, rz, dx, dy, dz, rw1, rw2, rw3;
    unsigned short uhx = bf16rn(ux, &rx), uhy = bf16rn(uy, &ry), uhz = bf16rn(uz, &rz);
    unsigned short ulx = bf16rn(rx, &dx), uly = bf16rn(ry, &dy), ulz = bf16rn(rz, &dz);
    unsigned short wh = bf16rn(w, &rw1), wm = bf16rn(rw1, &rw2), wl = bf16rn(rw2, &rw3);
    union { unsigned short s[16]; uint4 v[2]; } A;
    A.s[0] = uhx; A.s[1] = uhy; A.s[2]  = uhz;
    A.s[3] = uhx; A.s[4] = uhy; A.s[5]  = uhz;
    A.s[6] = ulx; A.s[7] = uly; A.s[8]  = ulz;
    A.s[9] = ulx; A.s[10] = uly; A.s[11] = ulz;
    A.s[12] = wh; A.s[13] = wm; A.s[14] = wl; A.s[15] = 0;
    TA[2 * (size_t)i]     = A.v[0];
    TA[2 * (size_t)i + 1] = A.v[1];

    float sx, sy, sz, ex, ey, ez;
    unsigned short qhx = bf16rn(x, &sx), qhy = bf16rn(y, &sy), qhz = bf16rn(z, &sz);
    unsigned short qlx = bf16rn(sx, &ex), qly = bf16rn(sy, &ey), qlz = bf16rn(sz, &ez);
    union { unsigned short s[16]; uint4 v[2]; } Bb;
    Bb.s[0] = qhx; Bb.s[1] = qhy; Bb.s[2]  = qhz;
    Bb.s[3] = qlx; Bb.s[4] = qly; Bb.s[5]  = qlz;
    Bb.s[6] = qhx; Bb.s[7] = qhy; Bb.s[8]  = qhz;
    Bb.s[9] = qlx; Bb.s[10] = qly; Bb.s[11] = qlz;
    Bb.s[12] = 0x3F80; Bb.s[13] = 0x3F80; Bb.s[14] = 0x3F80; Bb.s[15] = 0;
    TB[2 * (size_t)i]     = Bb.v[0];
    TB[2 * (size_t)i + 1] = Bb.v[1];
}

// async 16B global->LDS (direct-to-LDS DMA, no VGPR round-trip)
__device__ __forceinline__ void gload_lds16(const void* g, void* l) {
    __builtin_amdgcn_global_load_lds(
        (const __attribute__((address_space(1))) unsigned int*)g,
        (__attribute__((address_space(3))) unsigned int*)l, 16, 0, 0);
}

// elementwise min accumulate (depth-1, no reduction chain)
__device__ __forceinline__ f32x16 min16(f32x16 m, f32x16 d) {
#pragma unroll
    for (int j = 0; j < 16; ++j) m[j] = fminf(m[j], d[j]);
    return m;
}

// final 16 -> 1 tree (min3-fusable), once per kernel
__device__ __forceinline__ float mintree(f32x16 m) {
    float r0 = fminf(fminf(m[0], m[1]), m[2]);
    float r1 = fminf(fminf(m[3], m[4]), m[5]);
    float r2 = fminf(fminf(m[6], m[7]), m[8]);
    float r3 = fminf(fminf(m[9], m[10]), m[11]);
    float r4 = fminf(fminf(m[12], m[13]), m[14]);
    float s0 = fminf(fminf(r0, r1), r2);
    float s1 = fminf(fminf(r3, r4), m[15]);
    return fminf(s0, s1);
}

// grid (NPTS/QB=32, B_SZ=8, 2 dirs), 256 threads / 4 waves, 2 blocks/CU.
// Wave w: queries qb*256 + w*64 .. +63 (two 32-col B-sets).
__global__ __launch_bounds__(BLOCK, 2) void chamfer_nn_fused(
    const uint4* __restrict__ TgA, const uint4* __restrict__ TpB,
    const float* __restrict__ Wp,
    const uint4* __restrict__ TpA, const uint4* __restrict__ TgB,
    const float* __restrict__ Wg,
    float* __restrict__ out)
{
    __shared__ uint4 tileU[2 * SLICE * 2];   // 2 x 32 KiB A-form buffers
    __shared__ float psum[4];
    char* tileC = (char*)tileU;

    const int qb = blockIdx.x, b = blockIdx.y, dir = blockIdx.z;
    const int t = threadIdx.x, lane = t & 63, wid = t >> 6;
    const int col = lane & 31, hi = lane >> 5;

    const uint4* TA = dir ? TpA : TgA;
    const uint4* TB = dir ? TgB : TpB;
    const float* WQ = dir ? Wg  : Wp;

    // B fragments (round-4/6 exact addressing)
    const int qblk = qb * QB + wid * 64;
    const char* TBc = (const char*)(TB + ((size_t)b * NPTS + qblk) * 2);
    bf16x8 bq0 = *(const bf16x8*)(TBc + (size_t)col * 32 + hi * 16);
    bf16x8 bq1 = *(const bf16x8*)(TBc + (size_t)(col + 32) * 32 + hi * 16);

    f32x16 zacc;
#pragma unroll
    for (int j = 0; j < 16; ++j) zacc[j] = 0.f;
    f32x16 macc0 = zacc + 3.0e38f;           // elementwise init
    f32x16 macc1 = macc0;
    // swizzled A-frag READ base (unchanged, HW-proven since R4)
    const int abase = (col * 32 + hi * 16) ^ (((col >> 2) & 7) << 4);

    const uint4* TAb = TA + (size_t)b * NPTS * 2;
    // staging: LDS dest is LINEAR (wave-uniform base + lane*16); the swizzle
    // g -> g ^ ((g>>3)&7) (granules) is applied to the GLOBAL source lane
    // index instead — involution mixes only bits 0-2 with 3-5, i.e. stays
    // within the 64-granule lane span. Layout in LDS is byte-identical to
    // the R4/R6-proven granule-swizzled copy.
    const int swzlane = lane ^ (lane >> 3);
    const uint4* gsrc0 = TAb + wid * 512 + swzlane;
    char* ldst0 = tileC + wid * 8192;

    // prologue: stage 0 into buf0 (async; drained by the barrier's vmcnt)
#pragma unroll
    for (int it = 0; it < 8; ++it)
        gload_lds16(gsrc0 + it * 64, ldst0 + it * 1024);
    __syncthreads();

    for (int st = 0; st < NSTAGE; ++st) {
        const int cur = (st & 1) << 15;      // current buffer byte offset
        if (st + 1 < NSTAGE) {               // issue next stage EARLY (async)
            const uint4* gs = gsrc0 + (size_t)(st + 1) * (SLICE * 2);
            char* ld = ldst0 + (cur ^ 32768);
#pragma unroll
            for (int it = 0; it < 8; ++it)
                gload_lds16(gs + it * 64, ld + it * 1024);
        }

        // compute with a-lookahead; elementwise min (no carried scalar chain)
        const char* tb = tileC + cur + abase;
        bf16x8 a_cur = *(const bf16x8*)(tb);
#pragma unroll 2
        for (int tt = 0; tt < TILES - 1; ++tt) {
            bf16x8 a_nxt = *(const bf16x8*)(tb + (tt + 1) * 1024);
            f32x16 d0 = __builtin_amdgcn_mfma_f32_32x32x16_bf16(a_cur, bq0, zacc, 0, 0, 0);
            f32x16 d1 = __builtin_amdgcn_mfma_f32_32x32x16_bf16(a_cur, bq1, zacc, 0, 0, 0);
            macc0 = min16(macc0, d0);
            macc1 = min16(macc1, d1);
            a_cur = a_nxt;
        }
        f32x16 d0 = __builtin_amdgcn_mfma_f32_32x32x16_bf16(a_cur, bq0, zacc, 0, 0, 0);
        f32x16 d1 = __builtin_amdgcn_mfma_f32_32x32x16_bf16(a_cur, bq1, zacc, 0, 0, 0);
        macc0 = min16(macc0, d0);
        macc1 = min16(macc1, d1);

        __syncthreads();                     // one barrier/stage: drains the
                                             // async loads + fences buffers
    }

    // epilogue: 16->1 trees, combine row-halves, add ||q||^2  (R6 mapping)
    float m0 = mintree(macc0);
    float m1 = mintree(macc1);
    m0 = fminf(m0, __shfl_xor(m0, 32));
    m1 = fminf(m1, __shfl_xor(m1, 32));
    float wq = WQ[(size_t)b * NPTS + qb * QB + t];
    float d = fmaxf((lane < 32 ? m0 : m1) + wq, 0.0f);
    float s = d;
#pragma unroll
    for (int o = 1; o < 64; o <<= 1) s += __shfl_xor(s, o);
    if (lane == 0) psum[wid] = s;
    __syncthreads();
    if (t == 0) {
        float tot = (psum[0] + psum[1]) + (psum[2] + psum[3]);
        atomicAdd(out, tot * (1.0f / (float)TOTAL));
    }
}

extern "C" void kernel_launch(void* const* d_in, const int* in_sizes, int n_in,
                              void* d_out, int out_size, void* d_ws, size_t ws_size,
                              hipStream_t stream) {
    const float* pred = (const float*)d_in[0];   // [B, N, 3]
    const float* gt   = (const float*)d_in[1];   // [B, M, 3]
    float* out = (float*)d_out;

    // ws layout: TgA, TpA, TgB, TpB (32B/point), Wg, Wp
    char* ws = (char*)d_ws;
    uint4* TgA = (uint4*)(ws);
    uint4* TpA = (uint4*)(ws + (size_t)TOTAL * 32);
    uint4* TgB = (uint4*)(ws + (size_t)TOTAL * 64);
    uint4* TpB = (uint4*)(ws + (size_t)TOTAL * 96);
    float* Wg  = (float*)(ws + (size_t)TOTAL * 128);
    float* Wp  = (float*)(ws + (size_t)TOTAL * 128 + (size_t)TOTAL * 4);

    hipMemsetAsync(out, 0, sizeof(float), stream);

    chamfer_prep_mfma<<<dim3(TOTAL / BLOCK, 2), BLOCK, 0, stream>>>(
        gt, pred, TgA, TgB, Wg, TpA, TpB, Wp);

    chamfer_nn_fused<<<dim3(NPTS / QB, B_SZ, 2), BLOCK, 0, stream>>>(
        TgA, TpB, Wp, TpA, TgB, Wg, out);
}